// Round 8
// baseline (803.205 us; speedup 1.0000x reference)
//
#include <hip/hip_runtime.h>

// Problem constants (fixed by reference setup_inputs)
constexpr int Cc   = 3;
constexpr int Hc   = 160;
constexpr int Wc   = 160;
constexpr int Hoc  = 158;
constexpr int Woc  = 158;
constexpr int Lc   = Hoc * Woc;    // 24964
constexpr int Ntot = 4 * Lc;       // 99856
constexpr int NCH  = 8;
constexpr int MDd  = 54;           // 2 * C * 3 * 3

// Bijective (involutive) map float-bits <-> uint such that ascending uint
// == DESCENDING float. Applying it twice recovers the original bits.
__device__ __forceinline__ unsigned inv_key_bits(unsigned u) {
    return (u & 0x80000000u) ? u : (~u & 0x7FFFFFFFu);
}
__device__ __forceinline__ unsigned inv_key(float f) {
    return inv_key_bits(__float_as_uint(f));
}

// Compare-exchange on (key, weight) with NO 64-bit values anywhere.
// Rounds 3-7 measured ~12.5k cyc/wave for the u64-item sort: v_cmp_lt_u64
// pseudos + 54 even-aligned VGPR pairs are the cost, not the source op
// count. This CE is 5 unpaired 32-bit ops: cmp_le + min + max + 2 cndmask.
// '<=' (not '<') is essential: on equal keys, min/max keep operand order
// and the payload selects must agree, preserving key<->weight pairing.
__device__ __forceinline__ void ce(unsigned &ka, float &pa,
                                   unsigned &kb, float &pb) {
    const bool le = (ka <= kb);
    const unsigned klo = le ? ka : kb;
    const unsigned khi = le ? kb : ka;
    const float    plo = le ? pa : pb;
    const float    phi = le ? pb : pa;
    ka = klo; kb = khi; pa = plo; pb = phi;
}

__global__ __launch_bounds__(256) void wos_kernel(
    const float* __restrict__ x, const float* __restrict__ weight,
    const float* __restrict__ bias, const float* __restrict__ mask,
    float* __restrict__ out)
{
    const int lane = threadIdx.x & 63;
    const int wave = threadIdx.x >> 6;
    const int grp  = blockIdx.x >> 1;
    // nc is wave-uniform: assert it so weight/mask/bias reads become scalar loads.
    const int nc   = __builtin_amdgcn_readfirstlane(((blockIdx.x & 1) << 2) | wave);
    const int n    = grp * 64 + lane;
    if (n >= Ntot) return;

    const int b  = n / Lc;
    const int l  = n - b * Lc;
    const int ho = l / Woc;
    const int wo = l - ho * Woc;

    const float* xb = x + (b * Cc) * (Hc * Wc);
    const float* mk = mask + nc * MDd;      // wave-uniform -> scalar loads
    const float* wr = weight + nc * MDd;    // wave-uniform -> scalar loads
    const float  bi = bias[nc];

    // ks = exact 32-bit descending-order comparator key of mx (bit-faithful
    // fp32 order); pw = that element's weight (payload, swapped in lockstep).
    unsigned ks[MDd];
    float    pw[MDd];
    #pragma unroll
    for (int c = 0; c < 3; ++c) {
        #pragma unroll
        for (int r = 0; r < 3; ++r) {
            #pragma unroll
            for (int s = 0; s < 3; ++s) {
                const int d = c * 9 + r * 3 + s;
                const float v = xb[(c * Hc + ho + r) * Wc + wo + s];
                ks[d]      = inv_key( v + mk[d]);
                ks[27 + d] = inv_key(-v + mk[27 + d]);
                pw[d]      = wr[d];
                pw[27 + d] = wr[27 + d];
            }
        }
    }

    // Batcher odd-even mergesort for n=64, pruned to wires < 54 (monotone
    // network => virtual +inf pads on wires 54..63 never move down, so every
    // CE with hi >= 54 is a static no-op). Same ~450-CE network proven
    // absmax-0.0 in rounds 3-7; only the item representation changed.
    #pragma unroll
    for (int p = 1; p < 64; p <<= 1) {
        #pragma unroll
        for (int k = p; k >= 1; k >>= 1) {
            #pragma unroll
            for (int j = k % p; j + k < 64; j += 2 * k) {
                #pragma unroll
                for (int i = 0; i < k; ++i) {
                    const int lo = i + j;
                    const int hi = i + j + k;
                    if (hi < MDd && (lo / (2 * p) == hi / (2 * p))) {
                        ce(ks[lo], pw[lo], ks[hi], pw[hi]);
                    }
                }
            }
        }
    }

    // Sequential fp32 cumsum of weights in sorted (descending-mx) order —
    // bit-matches the reference. Track the key of the last rank whose
    // cumulative weight <= bias; default (clip-to-0) is rank 0's key.
    float acc = 0.0f;
    unsigned sel = ks[0];
    #pragma unroll
    for (int r = 0; r < MDd; ++r) {
        acc += pw[r];
        sel = (acc <= bi) ? ks[r] : sel;
    }

    // Invert the (involutive) key transform to recover the exact fp32 value.
    out[n * NCH + nc] = __uint_as_float(inv_key_bits(sel));
}

extern "C" void kernel_launch(void* const* d_in, const int* in_sizes, int n_in,
                              void* d_out, int out_size, void* d_ws, size_t ws_size,
                              hipStream_t stream) {
    const float* x      = (const float*)d_in[0];
    const float* weight = (const float*)d_in[1];
    const float* bias   = (const float*)d_in[2];
    const float* mask   = (const float*)d_in[3];
    float* out = (float*)d_out;

    const int ngrp = (Ntot + 63) / 64;      // 1561
    dim3 grid(ngrp * 2);                    // x2 blocks: 8 nc / 4 waves
    wos_kernel<<<grid, 256, 0, stream>>>(x, weight, bias, mask, out);
}

// Round 9
// 771.494 us; speedup vs baseline: 1.0411x; 1.0411x over previous
//
#include <hip/hip_runtime.h>

// Problem constants (fixed by reference setup_inputs)
constexpr int Cc   = 3;
constexpr int Hc   = 160;
constexpr int Wc   = 160;
constexpr int Hoc  = 158;
constexpr int Woc  = 158;
constexpr int Lc   = Hoc * Woc;    // 24964
constexpr int Ntot = 4 * Lc;       // 99856
constexpr int NCH  = 8;
constexpr int MDd  = 54;           // 2 * C * 3 * 3

// Bijective (involutive) map float-bits <-> uint: ascending uint == DESCENDING float.
__device__ __forceinline__ unsigned inv_key_bits(unsigned u) {
    return (u & 0x80000000u) ? u : (~u & 0x7FFFFFFFu);
}

// Recompute element idx's mx value from x/mask — bit-identical fp32 to the
// build phase (same adds, no contraction). idx in [0,54).
__device__ __forceinline__ float elem_val(unsigned idx, const float* __restrict__ xo,
                                          const float* __restrict__ mrow) {
    const bool neg = idx >= 27u;
    const unsigned d = neg ? idx - 27u : idx;
    const unsigned c = (d * 57u) >> 9;        // d/9 for d<27
    const unsigned rem = d - c * 9u;
    const unsigned r = (rem * 11u) >> 5;      // rem/3 for rem<9
    const unsigned s = rem - r * 3u;
    const float v = xo[c * (Hc * Wc) + r * Wc + s];
    const float m = mrow[idx];
    return neg ? (m - v) : (m + v);           // (-v)+m == m-v bitwise
}

__global__ __launch_bounds__(256) void wos_kernel(
    const float* __restrict__ x, const float* __restrict__ weight,
    const float* __restrict__ bias, const float* __restrict__ mask,
    float* __restrict__ out)
{
    // Per-nc weight table, stride 64 (cheap addressing). 2 KB only — rounds
    // 2-8 proved >100 live regs get demoted (AGPR shuttles or scratch), so
    // the sort holds ONE u32 array and weights are gathered from LDS.
    __shared__ float s_w[NCH * 64];
    for (int t = threadIdx.x; t < NCH * MDd; t += 256)
        s_w[(t / MDd) * 64 + (t % MDd)] = weight[t];
    __syncthreads();   // before any early-exit divergence

    const int lane = threadIdx.x & 63;
    const int wave = threadIdx.x >> 6;
    const int grp  = blockIdx.x >> 1;
    const int nc   = __builtin_amdgcn_readfirstlane(((blockIdx.x & 1) << 2) | wave);
    const int n    = grp * 64 + lane;
    if (n < Ntot) {
        const int b  = n / Lc;
        const int l  = n - b * Lc;
        const int ho = l / Woc;
        const int wo = l - ho * Woc;

        const float* xb = x + (b * Cc) * (Hc * Wc);
        const float* xo = xb + ho * Wc + wo;       // elem_val base
        const float* mk = mask + nc * MDd;         // wave-uniform -> scalar loads
        const float  bi = bias[nc];

        // Sort items: high 26 bits = truncated exact descending-order key of
        // mx, low 6 bits = source index (tie-break within a 64-ulp bucket;
        // wrong order there is REPAIRED below with exact keys).
        unsigned ks[MDd];
        #pragma unroll
        for (int c = 0; c < 3; ++c) {
            #pragma unroll
            for (int r = 0; r < 3; ++r) {
                #pragma unroll
                for (int s = 0; s < 3; ++s) {
                    const int d = c * 9 + r * 3 + s;
                    const float v = xb[(c * Hc + ho + r) * Wc + wo + s];
                    const unsigned f0 = inv_key_bits(__float_as_uint(v + mk[d]));
                    const unsigned f1 = inv_key_bits(__float_as_uint(-v + mk[27 + d]));
                    ks[d]      = (f0 & 0xFFFFFFC0u) | (unsigned)d;
                    ks[27 + d] = (f1 & 0xFFFFFFC0u) | (unsigned)(27 + d);
                }
            }
        }

        // Batcher odd-even mergesort, n=64 pruned to wires < 54 (monotone =>
        // +inf pads are static no-ops). Same network proven in rounds 3-8;
        // CE is now 2 instructions (v_min_u32/v_max_u32), ~54 live regs.
        #pragma unroll
        for (int p = 1; p < 64; p <<= 1) {
            #pragma unroll
            for (int k = p; k >= 1; k >>= 1) {
                #pragma unroll
                for (int j = k % p; j + k < 64; j += 2 * k) {
                    #pragma unroll
                    for (int i = 0; i < k; ++i) {
                        const int lo = i + j;
                        const int hi = i + j + k;
                        if (hi < MDd && (lo / (2 * p) == hi / (2 * p))) {
                            const unsigned a = ks[lo], c2 = ks[hi];
                            ks[lo] = a < c2 ? a : c2;   // v_min_u32
                            ks[hi] = a < c2 ? c2 : a;   // v_max_u32
                        }
                    }
                }
            }
        }

        // Detect truncation collisions: sorted => bucket-equal items are
        // adjacent; adjacent pair in same bucket iff xor < 64.
        unsigned coll = 0xFFFFFFFFu;
        #pragma unroll
        for (int r = 0; r + 1 < MDd; ++r) {
            const unsigned t = ks[r] ^ ks[r + 1];
            coll = coll < t ? coll : t;
        }

        if (__any(coll < 64u)) {
            // Rare (wave-uniform) repair: bubble sweeps restoring EXACT order
            // within trunc-equal runs, comparing recomputed full keys
            // (bit-identical to build). Strict '>' keeps exact ties in
            // index-ascending order == reference's stable argsort. 3 sweeps
            // handle runs up to length 4 (P(run>=4) ~ 1e-12).
            for (int pass = 0; pass < 3; ++pass) {
                unsigned fprev = inv_key_bits(__float_as_uint(elem_val(ks[0] & 63u, xo, mk)));
                #pragma unroll
                for (int r = 0; r + 1 < MDd; ++r) {
                    const unsigned a = ks[r], b2 = ks[r + 1];
                    const unsigned fb =
                        inv_key_bits(__float_as_uint(elem_val(b2 & 63u, xo, mk)));
                    const bool sw = ((a ^ b2) < 64u) && (fprev > fb);
                    ks[r]     = sw ? b2 : a;
                    ks[r + 1] = sw ? a : b2;
                    fprev     = sw ? fprev : fb;   // full key of new ks[r+1]
                }
            }
        }

        // Sequential fp32 cumsum of weights in sorted (descending-mx) order —
        // bit-matches the reference's cumsum. Track last rank with acc <= bias.
        const float* wrow = &s_w[nc << 6];
        float acc = 0.0f;
        unsigned sel = ks[0];
        #pragma unroll
        for (int r = 0; r < MDd; ++r) {
            acc += wrow[ks[r] & 63u];
            sel = (acc <= bi) ? ks[r] : sel;
        }

        // Recompute the selected element's exact fp32 value from its index.
        out[n * NCH + nc] = elem_val(sel & 63u, xo, mk);
    }
}

extern "C" void kernel_launch(void* const* d_in, const int* in_sizes, int n_in,
                              void* d_out, int out_size, void* d_ws, size_t ws_size,
                              hipStream_t stream) {
    const float* x      = (const float*)d_in[0];
    const float* weight = (const float*)d_in[1];
    const float* bias   = (const float*)d_in[2];
    const float* mask   = (const float*)d_in[3];
    float* out = (float*)d_out;

    const int ngrp = (Ntot + 63) / 64;      // 1561
    dim3 grid(ngrp * 2);                    // x2 blocks: 8 nc / 4 waves
    wos_kernel<<<grid, 256, 0, stream>>>(x, weight, bias, mask, out);
}